// Round 3
// baseline (810.217 us; speedup 1.0000x reference)
//
#include <hip/hip_runtime.h>

#define N_NODES  100000
#define N_EDGES  3200000
#define N_GRAPHS 512
#define F_IN     5
#define F_HID    16

#define PBLK   512                      // sort block size
#define CHUNK  4096                     // edges per sort block
#define NBLK   ((N_EDGES + CHUNK - 1) / CHUNK)          // 782
#define BKT_NODES 256                   // nodes per bucket
#define NBKT ((N_NODES + BKT_NODES - 1) / BKT_NODES)    // 391
#define HPAD   512                      // H row stride
#define CAP    10240                    // per-bucket segment capacity (mean 8184, +23 sigma)

// ---------------- helpers ----------------

__device__ inline unsigned short f2bf(float f) {
    unsigned u = __float_as_uint(f);
    return (unsigned short)((u + 0x7fffu + ((u >> 16) & 1u)) >> 16);   // RNE
}
__device__ inline float bf2f(unsigned short h) {
    return __uint_as_float(((unsigned)h) << 16);
}
// unpack one 32 B bf16 row (2 x uint4) into 16 floats
__device__ inline void unpack16(uint4 r0, uint4 r1, float* f) {
    f[0]  = bf2f((unsigned short)r0.x); f[1]  = bf2f((unsigned short)(r0.x >> 16));
    f[2]  = bf2f((unsigned short)r0.y); f[3]  = bf2f((unsigned short)(r0.y >> 16));
    f[4]  = bf2f((unsigned short)r0.z); f[5]  = bf2f((unsigned short)(r0.z >> 16));
    f[6]  = bf2f((unsigned short)r0.w); f[7]  = bf2f((unsigned short)(r0.w >> 16));
    f[8]  = bf2f((unsigned short)r1.x); f[9]  = bf2f((unsigned short)(r1.x >> 16));
    f[10] = bf2f((unsigned short)r1.y); f[11] = bf2f((unsigned short)(r1.y >> 16));
    f[12] = bf2f((unsigned short)r1.z); f[13] = bf2f((unsigned short)(r1.z >> 16));
    f[14] = bf2f((unsigned short)r1.w); f[15] = bf2f((unsigned short)(r1.w >> 16));
}

// block-wide inclusive scan via wave shfl; NW = number of waves (<=8)
template <int NW>
__device__ inline int block_incl_scan(int v, int t, int* wsum) {
    int lane = t & 63, wave = t >> 6;
    int x = v;
#pragma unroll
    for (int o = 1; o < 64; o <<= 1) {
        int y = __shfl_up(x, o, 64);
        if (lane >= o) x += y;
    }
    if (lane == 63) wsum[wave] = x;
    __syncthreads();
    if (t < 64) {
        int w = (t < NW) ? wsum[t] : 0;
#pragma unroll
        for (int o = 1; o < NW; o <<= 1) {
            int y = __shfl_up(w, o, 64);
            if (t >= o) w += y;
        }
        if (t < NW) wsum[t] = w;
    }
    __syncthreads();
    return x + (wave ? wsum[wave - 1] : 0);
}

// ---------------- kernels ----------------

__global__ void k_zero(float* __restrict__ out, float* __restrict__ cnt) {
    int i = blockIdx.x * blockDim.x + threadIdx.x;
    if (i < N_GRAPHS * F_HID) out[i] = 0.0f;
    if (i < N_GRAPHS) cnt[i] = 0.0f;
}

// phase 1 of 3-phase counting sort: per-block histogram of dst>>8, written
// atomics-free to H[blk][bucket]. Blocks blk < NBKT also count nodes-per-graph
// from the sorted batch array (block b covers nodes [b*256, b*256+256)).
__global__ __launch_bounds__(PBLK) void k_count(const int* __restrict__ dst,
                                                const int* __restrict__ batch,
                                                int* __restrict__ H,
                                                float* __restrict__ cnt) {
    __shared__ int hist[HPAD];
    __shared__ int bcnt[8];
    __shared__ int g0s;
    int t = threadIdx.x, blk = blockIdx.x;
    int chunk0 = blk * CHUNK;
    int n4 = min(CHUNK, N_EDGES - chunk0) >> 2;
    hist[t] = 0;
    if (t < 8) bcnt[t] = 0;
    if (t == 0 && blk < NBKT) {
        int nb = blk * BKT_NODES;
        g0s = batch[nb < N_NODES ? nb : N_NODES - 1];
    }
    __syncthreads();
    const int4* d4 = (const int4*)(dst + chunk0);
#pragma unroll
    for (int i = 0; i < CHUNK / 4 / PBLK; i++) {
        int k = t + i * PBLK;
        if (k < n4) {
            int4 d = d4[k];
            atomicAdd(&hist[d.x >> 8], 1);
            atomicAdd(&hist[d.y >> 8], 1);
            atomicAdd(&hist[d.z >> 8], 1);
            atomicAdd(&hist[d.w >> 8], 1);
        }
    }
    if (blk < NBKT && t < BKT_NODES) {
        int i2 = blk * BKT_NODES + t;
        if (i2 < N_NODES) {
            int g = batch[i2];
            int l = g - g0s;
            if (l >= 0 && l < 8) atomicAdd(&bcnt[l], 1);
            else atomicAdd(&cnt[g], 1.0f);
        }
    }
    __syncthreads();
    H[blk * HPAD + t] = hist[t];                    // coalesced, no atomics
    if (blk < NBKT && t < 8 && bcnt[t] > 0) atomicAdd(&cnt[g0s + t], (float)bcnt[t]);
}

// phase 2: per bucket, exclusive scan of counts across blocks (in place),
// exact bucket total -> cnt_b. One block per bucket.
__global__ __launch_bounds__(256) void k_scan(int* __restrict__ H,
                                              int* __restrict__ cnt_b) {
    __shared__ int wsum[8];
    int b = blockIdx.x, t = threadIdx.x;
    int v[4];
    int s = 0;
#pragma unroll
    for (int i = 0; i < 4; i++) {
        int pos = t * 4 + i;
        v[i] = (pos < NBLK) ? H[pos * HPAD + b] : 0;
        s += v[i];
    }
    int incl = block_incl_scan<4>(s, t, wsum);
    int run = incl - s;
#pragma unroll
    for (int i = 0; i < 4; i++) {
        int pos = t * 4 + i;
        if (pos < NBLK) H[pos * HPAD + b] = run;
        run += v[i];
    }
    if (t == 255) cnt_b[b] = incl;                  // grand total for bucket b
}

// phase 3: re-read edges, block-local counting sort into LDS, then a
// coalesced flush to exact precomputed global positions. No global atomics.
__global__ __launch_bounds__(PBLK) void k_scatter(const int* __restrict__ src,
                                                  const int* __restrict__ dst,
                                                  const int* __restrict__ H,
                                                  unsigned* __restrict__ packed) {
    __shared__ int hist[HPAD];
    __shared__ int scn[HPAD];
    __shared__ int rnk[HPAD];
    __shared__ int base[HPAD];
    __shared__ int wsum[8];
    __shared__ unsigned pkd[CHUNK];                 // 16 KiB
    __shared__ unsigned short bkt[CHUNK];           // 8 KiB
    int t = threadIdx.x, blk = blockIdx.x;
    int chunk0 = blk * CHUNK;
    int n = min(CHUNK, N_EDGES - chunk0);
    int n4 = n >> 2;
    hist[t] = 0;
    base[t] = H[blk * HPAD + t];                    // coalesced scanned bases
    __syncthreads();
    const int4* s4 = (const int4*)(src + chunk0);
    const int4* d4 = (const int4*)(dst + chunk0);
    int4 lsv[CHUNK / 4 / PBLK], ldv[CHUNK / 4 / PBLK];
#pragma unroll
    for (int i = 0; i < CHUNK / 4 / PBLK; i++) {    // static idx -> registers
        int k = t + i * PBLK;
        if (k < n4) {
            lsv[i] = s4[k];
            ldv[i] = d4[k];
            atomicAdd(&hist[ldv[i].x >> 8], 1);
            atomicAdd(&hist[ldv[i].y >> 8], 1);
            atomicAdd(&hist[ldv[i].z >> 8], 1);
            atomicAdd(&hist[ldv[i].w >> 8], 1);
        }
    }
    __syncthreads();
    int v = hist[t];
    int incl = block_incl_scan<8>(v, t, wsum);
    int excl = incl - v;
    scn[t] = excl;
    rnk[t] = excl;
    __syncthreads();
#pragma unroll
    for (int i = 0; i < CHUNK / 4 / PBLK; i++) {
        int k = t + i * PBLK;
        if (k < n4) {
            int ds0 = ldv[i].x, ds1 = ldv[i].y, ds2 = ldv[i].z, ds3 = ldv[i].w;
            int ss0 = lsv[i].x, ss1 = lsv[i].y, ss2 = lsv[i].z, ss3 = lsv[i].w;
            int b0 = ds0 >> 8, b1 = ds1 >> 8, b2 = ds2 >> 8, b3 = ds3 >> 8;
            int r0 = atomicAdd(&rnk[b0], 1);
            pkd[r0] = ((unsigned)ss0 << 8) | (unsigned)(ds0 & 255);
            bkt[r0] = (unsigned short)b0;
            int r1 = atomicAdd(&rnk[b1], 1);
            pkd[r1] = ((unsigned)ss1 << 8) | (unsigned)(ds1 & 255);
            bkt[r1] = (unsigned short)b1;
            int r2 = atomicAdd(&rnk[b2], 1);
            pkd[r2] = ((unsigned)ss2 << 8) | (unsigned)(ds2 & 255);
            bkt[r2] = (unsigned short)b2;
            int r3 = atomicAdd(&rnk[b3], 1);
            pkd[r3] = ((unsigned)ss3 << 8) | (unsigned)(ds3 & 255);
            bkt[r3] = (unsigned short)b3;
        }
    }
    __syncthreads();
    for (int p = t; p < n; p += PBLK) {             // coalesced flush
        int b = bkt[p];
        packed[(size_t)b * CAP + base[b] + (p - scn[b])] = pkd[p];
    }
}

// per bucket: node degrees (LDS hist over the dense segment) -> dinv, and
// fused layer-1 transform pb = bf16((x @ W1) * dinv). No sort, no col.
__global__ __launch_bounds__(1024) void k_deg(const int* __restrict__ cnt_b,
                                              const unsigned* __restrict__ packed,
                                              const float* __restrict__ x,
                                              const float* __restrict__ W1,
                                              float* __restrict__ dinv,
                                              unsigned short* __restrict__ pb) {
    __shared__ int hist[BKT_NODES];
    __shared__ float w1[F_IN * F_HID];
    __shared__ int tots;
    int b = blockIdx.x, t = threadIdx.x;
    if (t < BKT_NODES) hist[t] = 0;
    if (t >= 256 && t < 256 + F_IN * F_HID) w1[t - 256] = W1[t - 256];
    if (t == 0) tots = min(cnt_b[b], CAP);
    __syncthreads();
    int tot = tots;
    const unsigned* pk = packed + (size_t)b * CAP;
    for (int k = t; k < tot; k += 1024)
        atomicAdd(&hist[pk[k] & 255], 1);
    __syncthreads();
    if (t < BKT_NODES) {
        int node = b * BKT_NODES + t;
        if (node < N_NODES) {
            float di = rsqrtf((float)(1 + hist[t]));   // +1 self loop
            dinv[node] = di;
            float xi[F_IN];
#pragma unroll
            for (int k = 0; k < F_IN; k++) xi[k] = x[node * F_IN + k];
            unsigned pkk[8];
#pragma unroll
            for (int q = 0; q < 8; q++) {
                float h0 = 0.0f, h1 = 0.0f;
#pragma unroll
                for (int k = 0; k < F_IN; k++) {
                    h0 += xi[k] * w1[k * F_HID + 2 * q];
                    h1 += xi[k] * w1[k * F_HID + 2 * q + 1];
                }
                pkk[q] = (unsigned)f2bf(h0 * di) | ((unsigned)f2bf(h1 * di) << 16);
            }
            uint4* d4 = (uint4*)(pb + (size_t)node * F_HID);
            d4[0] = make_uint4(pkk[0], pkk[1], pkk[2], pkk[3]);
            d4[1] = make_uint4(pkk[4], pkk[5], pkk[6], pkk[7]);
        }
    }
}

// layer-1 aggregation, push-mode per bucket: LDS accT[ch][node] (bank = node&31
// -> per-channel ds_add waves spread ~2/bank), self-loop via init, then fused
// epilogue h1 = relu(di*acc + b1); pb2 = bf16((h1 @ W2) * di).
__global__ __launch_bounds__(1024) void k_agg1(const int* __restrict__ cnt_b,
                                               const unsigned* __restrict__ packed,
                                               const unsigned short* __restrict__ pb,
                                               const float* __restrict__ dinv,
                                               const float* __restrict__ W2,
                                               const float* __restrict__ b1,
                                               unsigned short* __restrict__ pb2) {
    __shared__ float accT[F_HID][BKT_NODES];        // 16 KiB, [ch][node_local]
    __shared__ float w2[F_HID * F_HID];
    __shared__ float b1s[F_HID];
    __shared__ int tots;
    int b = blockIdx.x, t = threadIdx.x;
    const uint4* pb16 = (const uint4*)pb;
    if (t == 0) tots = min(cnt_b[b], CAP);
    if (t >= 256 && t < 512) w2[t - 256] = W2[t - 256];
    if (t >= 512 && t < 512 + F_HID) b1s[t - 512] = b1[t - 512];
    if (t < BKT_NODES) {                            // self-loop init
        int node = b * BKT_NODES + t;
        if (node < N_NODES) {
            float f[F_HID];
            unpack16(pb16[node * 2], pb16[node * 2 + 1], f);
#pragma unroll
            for (int c = 0; c < F_HID; c++) accT[c][t] = f[c];
        } else {
#pragma unroll
            for (int c = 0; c < F_HID; c++) accT[c][t] = 0.0f;
        }
    }
    __syncthreads();
    int tot = tots;
    const unsigned* pk = packed + (size_t)b * CAP;
    for (int k = t; k < tot; k += 1024) {
        unsigned u = pk[k];
        int srcn = (int)(u >> 8);
        int dl = (int)(u & 255);
        float f[F_HID];
        unpack16(pb16[srcn * 2], pb16[srcn * 2 + 1], f);
#pragma unroll
        for (int c = 0; c < F_HID; c++) atomicAdd(&accT[c][dl], f[c]);
    }
    __syncthreads();
    if (t < 512) {
        int nl = t >> 1, hh = t & 1;                // 2 threads/node, 8 outputs each
        int node = b * BKT_NODES + nl;
        if (node < N_NODES) {
            float di = dinv[node];
            float h[F_HID];
#pragma unroll
            for (int c = 0; c < F_HID; c++)
                h[c] = fmaxf(di * accT[c][nl] + b1s[c], 0.0f);
            unsigned pkk[4];
#pragma unroll
            for (int q = 0; q < 4; q++) {
                int c0 = hh * 8 + 2 * q;
                float m0 = 0.0f, m1 = 0.0f;
#pragma unroll
                for (int c = 0; c < F_HID; c++) {
                    m0 += h[c] * w2[c * F_HID + c0];
                    m1 += h[c] * w2[c * F_HID + c0 + 1];
                }
                pkk[q] = (unsigned)f2bf(m0 * di) | ((unsigned)f2bf(m1 * di) << 16);
            }
            ((uint4*)(pb2 + (size_t)node * F_HID))[hh] =
                make_uint4(pkk[0], pkk[1], pkk[2], pkk[3]);
        }
    }
}

// layer-2 aggregation + fused mean-pool: same push-mode, epilogue writes
// h2 = relu(di*acc + b2) back into accT, then a staggered column-scan sums
// each (local graph, channel) over the bucket's 256 nodes (16 slots is
// unreachable-safe: min graph size ~146 >> 256/15). One global atomic per
// (graph,channel) per bucket.
__global__ __launch_bounds__(1024) void k_agg2(const int* __restrict__ cnt_b,
                                               const unsigned* __restrict__ packed,
                                               const unsigned short* __restrict__ pb,
                                               const float* __restrict__ dinv,
                                               const int* __restrict__ batch,
                                               const float* __restrict__ b2,
                                               const float* __restrict__ cnt,
                                               float* __restrict__ out) {
    __shared__ float accT[F_HID][BKT_NODES];        // 16 KiB
    __shared__ float b2s[F_HID];
    __shared__ int bl[BKT_NODES];
    __shared__ int tots;
    int b = blockIdx.x, t = threadIdx.x;
    const uint4* pb16 = (const uint4*)pb;
    if (t == 0) tots = min(cnt_b[b], CAP);
    if (t >= 512 && t < 512 + F_HID) b2s[t - 512] = b2[t - 512];
    if (t < BKT_NODES) {
        int node = b * BKT_NODES + t;
        if (node < N_NODES) {
            bl[t] = batch[node];
            float f[F_HID];
            unpack16(pb16[node * 2], pb16[node * 2 + 1], f);
#pragma unroll
            for (int c = 0; c < F_HID; c++) accT[c][t] = f[c];
        } else {
            bl[t] = -1;
#pragma unroll
            for (int c = 0; c < F_HID; c++) accT[c][t] = 0.0f;
        }
    }
    __syncthreads();
    int tot = tots;
    const unsigned* pk = packed + (size_t)b * CAP;
    for (int k = t; k < tot; k += 1024) {
        unsigned u = pk[k];
        int srcn = (int)(u >> 8);
        int dl = (int)(u & 255);
        float f[F_HID];
        unpack16(pb16[srcn * 2], pb16[srcn * 2 + 1], f);
#pragma unroll
        for (int c = 0; c < F_HID; c++) atomicAdd(&accT[c][dl], f[c]);
    }
    __syncthreads();
    if (t < BKT_NODES) {                            // h2 in place
        int node = b * BKT_NODES + t;
        if (node < N_NODES) {
            float di = dinv[node];
#pragma unroll
            for (int c = 0; c < F_HID; c++)
                accT[c][t] = fmaxf(di * accT[c][t] + b2s[c], 0.0f);
        }
    }
    __syncthreads();
    if (t < 256) {                                  // (local graph l, channel ch)
        int l = t >> 4, ch = t & 15;
        int g = bl[0] + l;
        if (g < N_GRAPHS) {
            float s = 0.0f;
            int m = 0;
            for (int n0 = 0; n0 < 256; n0++) {
                int n = (n0 + ch + 16 * l) & 255;   // 2-way bank stagger
                if (bl[n] == g) { s += accT[ch][n]; m++; }
            }
            if (m > 0) atomicAdd(&out[g * F_HID + ch], s / cnt[g]);
        }
    }
}

// ---------------- launcher ----------------

extern "C" void kernel_launch(void* const* d_in, const int* in_sizes, int n_in,
                              void* d_out, int out_size, void* d_ws, size_t ws_size,
                              hipStream_t stream) {
    const float* x     = (const float*)d_in[0];
    const int*   ei    = (const int*)d_in[1];   // [2, N_EDGES]
    const int*   batch = (const int*)d_in[2];
    const float* W1    = (const float*)d_in[3];
    const float* b1    = (const float*)d_in[4];
    const float* W2    = (const float*)d_in[5];
    const float* b2    = (const float*)d_in[6];
    float* out = (float*)d_out;

    int*            H      = (int*)d_ws;                                   // NBLK*HPAD
    int*            cnt_b  = H + (size_t)NBLK * HPAD;                      // 512
    unsigned*       packed = (unsigned*)(cnt_b + 512);                     // NBKT*CAP
    float*          dinv   = (float*)(packed + (size_t)NBKT * CAP);        // N
    unsigned short* pb_a   = (unsigned short*)(dinv + N_NODES);            // N*16 (32B-aligned)
    unsigned short* pb_b   = pb_a + (size_t)N_NODES * F_HID;               // N*16
    float*          cnt    = (float*)(pb_b + (size_t)N_NODES * F_HID);     // 512

    const int* src = ei;
    const int* dst = ei + N_EDGES;

    k_zero<<<(N_GRAPHS * F_HID + 255) / 256, 256, 0, stream>>>(out, cnt);
    k_count<<<NBLK, PBLK, 0, stream>>>(dst, batch, H, cnt);
    k_scan<<<NBKT, 256, 0, stream>>>(H, cnt_b);
    k_scatter<<<NBLK, PBLK, 0, stream>>>(src, dst, H, packed);
    k_deg<<<NBKT, 1024, 0, stream>>>(cnt_b, packed, x, W1, dinv, pb_a);
    k_agg1<<<NBKT, 1024, 0, stream>>>(cnt_b, packed, pb_a, dinv, W2, b1, pb_b);
    k_agg2<<<NBKT, 1024, 0, stream>>>(cnt_b, packed, pb_b, dinv, batch, b2, cnt, out);
}

// Round 4
// 187.187 us; speedup vs baseline: 4.3284x; 4.3284x over previous
//
#include <hip/hip_runtime.h>

#define N_NODES  100000
#define N_EDGES  3200000
#define N_GRAPHS 512
#define F_IN     5
#define F_HID    16

#define PBLK   512                      // sort block size
#define CHUNK  4096                     // edges per sort block
#define NBLK   ((N_EDGES + CHUNK - 1) / CHUNK)          // 782
#define BKT_NODES 256                   // nodes per bucket
#define NBKT ((N_NODES + BKT_NODES - 1) / BKT_NODES)    // 391
#define HPAD   512                      // H row stride
#define CAP    10240                    // per-bucket segment capacity (mean 8184, +23 sigma)

// ---------------- helpers ----------------

__device__ inline unsigned short f2bf(float f) {
    unsigned u = __float_as_uint(f);
    return (unsigned short)((u + 0x7fffu + ((u >> 16) & 1u)) >> 16);   // RNE
}
__device__ inline float bf2f(unsigned short h) {
    return __uint_as_float(((unsigned)h) << 16);
}
// unpack one 32 B bf16 row (2 x uint4) into 16 floats
__device__ inline void unpack16(uint4 r0, uint4 r1, float* f) {
    f[0]  = bf2f((unsigned short)r0.x); f[1]  = bf2f((unsigned short)(r0.x >> 16));
    f[2]  = bf2f((unsigned short)r0.y); f[3]  = bf2f((unsigned short)(r0.y >> 16));
    f[4]  = bf2f((unsigned short)r0.z); f[5]  = bf2f((unsigned short)(r0.z >> 16));
    f[6]  = bf2f((unsigned short)r0.w); f[7]  = bf2f((unsigned short)(r0.w >> 16));
    f[8]  = bf2f((unsigned short)r1.x); f[9]  = bf2f((unsigned short)(r1.x >> 16));
    f[10] = bf2f((unsigned short)r1.y); f[11] = bf2f((unsigned short)(r1.y >> 16));
    f[12] = bf2f((unsigned short)r1.z); f[13] = bf2f((unsigned short)(r1.z >> 16));
    f[14] = bf2f((unsigned short)r1.w); f[15] = bf2f((unsigned short)(r1.w >> 16));
}

// block-wide inclusive scan via wave shfl; NW = number of waves (<=16)
template <int NW>
__device__ inline int block_incl_scan(int v, int t, int* wsum) {
    int lane = t & 63, wave = t >> 6;
    int x = v;
#pragma unroll
    for (int o = 1; o < 64; o <<= 1) {
        int y = __shfl_up(x, o, 64);
        if (lane >= o) x += y;
    }
    if (lane == 63) wsum[wave] = x;
    __syncthreads();
    if (t < 64) {
        int w = (t < NW) ? wsum[t] : 0;
#pragma unroll
        for (int o = 1; o < NW; o <<= 1) {
            int y = __shfl_up(w, o, 64);
            if (t >= o) w += y;
        }
        if (t < NW) wsum[t] = w;
    }
    __syncthreads();
    return x + (wave ? wsum[wave - 1] : 0);
}

// ---------------- kernels ----------------

__global__ void k_zero(float* __restrict__ out, float* __restrict__ cnt) {
    int i = blockIdx.x * blockDim.x + threadIdx.x;
    if (i < N_GRAPHS * F_HID) out[i] = 0.0f;
    if (i < N_GRAPHS) cnt[i] = 0.0f;
}

// phase 1 of 3-phase counting sort: per-block histogram of dst>>8, written
// atomics-free to H[blk][bucket]. Blocks blk < NBKT also count nodes-per-graph
// from the sorted batch array (block b covers nodes [b*256, b*256+256)).
__global__ __launch_bounds__(PBLK) void k_count(const int* __restrict__ dst,
                                                const int* __restrict__ batch,
                                                int* __restrict__ H,
                                                float* __restrict__ cnt) {
    __shared__ int hist[HPAD];
    __shared__ int bcnt[8];
    __shared__ int g0s;
    int t = threadIdx.x, blk = blockIdx.x;
    int chunk0 = blk * CHUNK;
    int n4 = min(CHUNK, N_EDGES - chunk0) >> 2;
    hist[t] = 0;
    if (t < 8) bcnt[t] = 0;
    if (t == 0 && blk < NBKT) {
        int nb = blk * BKT_NODES;
        g0s = batch[nb < N_NODES ? nb : N_NODES - 1];
    }
    __syncthreads();
    const int4* d4 = (const int4*)(dst + chunk0);
#pragma unroll
    for (int i = 0; i < CHUNK / 4 / PBLK; i++) {
        int k = t + i * PBLK;
        if (k < n4) {
            int4 d = d4[k];
            atomicAdd(&hist[d.x >> 8], 1);
            atomicAdd(&hist[d.y >> 8], 1);
            atomicAdd(&hist[d.z >> 8], 1);
            atomicAdd(&hist[d.w >> 8], 1);
        }
    }
    if (blk < NBKT && t < BKT_NODES) {
        int i2 = blk * BKT_NODES + t;
        if (i2 < N_NODES) {
            int g = batch[i2];
            int l = g - g0s;
            if (l >= 0 && l < 8) atomicAdd(&bcnt[l], 1);
            else atomicAdd(&cnt[g], 1.0f);
        }
    }
    __syncthreads();
    H[blk * HPAD + t] = hist[t];                    // coalesced, no atomics
    if (blk < NBKT && t < 8 && bcnt[t] > 0) atomicAdd(&cnt[g0s + t], (float)bcnt[t]);
}

// phase 2: per bucket, exclusive scan of counts across blocks (in place),
// exact bucket total -> cnt_b. One block per bucket.
__global__ __launch_bounds__(256) void k_scan(int* __restrict__ H,
                                              int* __restrict__ cnt_b) {
    __shared__ int wsum[8];
    int b = blockIdx.x, t = threadIdx.x;
    int v[4];
    int s = 0;
#pragma unroll
    for (int i = 0; i < 4; i++) {
        int pos = t * 4 + i;
        v[i] = (pos < NBLK) ? H[pos * HPAD + b] : 0;
        s += v[i];
    }
    int incl = block_incl_scan<4>(s, t, wsum);
    int run = incl - s;
#pragma unroll
    for (int i = 0; i < 4; i++) {
        int pos = t * 4 + i;
        if (pos < NBLK) H[pos * HPAD + b] = run;
        run += v[i];
    }
    if (t == 255) cnt_b[b] = incl;                  // grand total for bucket b
}

// phase 3: re-read edges, block-local counting sort into LDS, then a
// coalesced flush to exact precomputed global positions. No global atomics.
__global__ __launch_bounds__(PBLK) void k_scatter(const int* __restrict__ src,
                                                  const int* __restrict__ dst,
                                                  const int* __restrict__ H,
                                                  unsigned* __restrict__ packed) {
    __shared__ int hist[HPAD];
    __shared__ int scn[HPAD];
    __shared__ int rnk[HPAD];
    __shared__ int base[HPAD];
    __shared__ int wsum[8];
    __shared__ unsigned pkd[CHUNK];                 // 16 KiB
    __shared__ unsigned short bkt[CHUNK];           // 8 KiB
    int t = threadIdx.x, blk = blockIdx.x;
    int chunk0 = blk * CHUNK;
    int n = min(CHUNK, N_EDGES - chunk0);
    int n4 = n >> 2;
    hist[t] = 0;
    base[t] = H[blk * HPAD + t];                    // coalesced scanned bases
    __syncthreads();
    const int4* s4 = (const int4*)(src + chunk0);
    const int4* d4 = (const int4*)(dst + chunk0);
    int4 lsv[CHUNK / 4 / PBLK], ldv[CHUNK / 4 / PBLK];
#pragma unroll
    for (int i = 0; i < CHUNK / 4 / PBLK; i++) {    // static idx -> registers
        int k = t + i * PBLK;
        if (k < n4) {
            lsv[i] = s4[k];
            ldv[i] = d4[k];
            atomicAdd(&hist[ldv[i].x >> 8], 1);
            atomicAdd(&hist[ldv[i].y >> 8], 1);
            atomicAdd(&hist[ldv[i].z >> 8], 1);
            atomicAdd(&hist[ldv[i].w >> 8], 1);
        }
    }
    __syncthreads();
    int v = hist[t];
    int incl = block_incl_scan<8>(v, t, wsum);
    int excl = incl - v;
    scn[t] = excl;
    rnk[t] = excl;
    __syncthreads();
#pragma unroll
    for (int i = 0; i < CHUNK / 4 / PBLK; i++) {
        int k = t + i * PBLK;
        if (k < n4) {
            int ds0 = ldv[i].x, ds1 = ldv[i].y, ds2 = ldv[i].z, ds3 = ldv[i].w;
            int ss0 = lsv[i].x, ss1 = lsv[i].y, ss2 = lsv[i].z, ss3 = lsv[i].w;
            int b0 = ds0 >> 8, b1 = ds1 >> 8, b2 = ds2 >> 8, b3 = ds3 >> 8;
            int r0 = atomicAdd(&rnk[b0], 1);
            pkd[r0] = ((unsigned)ss0 << 8) | (unsigned)(ds0 & 255);
            bkt[r0] = (unsigned short)b0;
            int r1 = atomicAdd(&rnk[b1], 1);
            pkd[r1] = ((unsigned)ss1 << 8) | (unsigned)(ds1 & 255);
            bkt[r1] = (unsigned short)b1;
            int r2 = atomicAdd(&rnk[b2], 1);
            pkd[r2] = ((unsigned)ss2 << 8) | (unsigned)(ds2 & 255);
            bkt[r2] = (unsigned short)b2;
            int r3 = atomicAdd(&rnk[b3], 1);
            pkd[r3] = ((unsigned)ss3 << 8) | (unsigned)(ds3 & 255);
            bkt[r3] = (unsigned short)b3;
        }
    }
    __syncthreads();
    for (int p = t; p < n; p += PBLK) {             // coalesced flush
        int b = bkt[p];
        packed[(size_t)b * CAP + base[b] + (p - scn[b])] = pkd[p];
    }
}

// per bucket: node degrees (LDS int hist over the dense segment) -> dinv, and
// fused layer-1 transform pb = bf16((x @ W1) * dinv).
__global__ __launch_bounds__(1024) void k_deg(const int* __restrict__ cnt_b,
                                              const unsigned* __restrict__ packed,
                                              const float* __restrict__ x,
                                              const float* __restrict__ W1,
                                              float* __restrict__ dinv,
                                              unsigned short* __restrict__ pb) {
    __shared__ int hist[BKT_NODES];
    __shared__ float w1[F_IN * F_HID];
    __shared__ int tots;
    int b = blockIdx.x, t = threadIdx.x;
    if (t < BKT_NODES) hist[t] = 0;
    if (t >= 256 && t < 256 + F_IN * F_HID) w1[t - 256] = W1[t - 256];
    if (t == 0) tots = min(cnt_b[b], CAP);
    __syncthreads();
    int tot = tots;
    const unsigned* pk = packed + (size_t)b * CAP;
    for (int k = t; k < tot; k += 1024)
        atomicAdd(&hist[pk[k] & 255], 1);
    __syncthreads();
    if (t < BKT_NODES) {
        int node = b * BKT_NODES + t;
        if (node < N_NODES) {
            float di = rsqrtf((float)(1 + hist[t]));   // +1 self loop
            dinv[node] = di;
            float xi[F_IN];
#pragma unroll
            for (int k = 0; k < F_IN; k++) xi[k] = x[node * F_IN + k];
            unsigned pkk[8];
#pragma unroll
            for (int q = 0; q < 8; q++) {
                float h0 = 0.0f, h1 = 0.0f;
#pragma unroll
                for (int k = 0; k < F_IN; k++) {
                    h0 += xi[k] * w1[k * F_HID + 2 * q];
                    h1 += xi[k] * w1[k * F_HID + 2 * q + 1];
                }
                pkk[q] = (unsigned)f2bf(h0 * di) | ((unsigned)f2bf(h1 * di) << 16);
            }
            uint4* d4 = (uint4*)(pb + (size_t)node * F_HID);
            d4[0] = make_uint4(pkk[0], pkk[1], pkk[2], pkk[3]);
            d4[1] = make_uint4(pkk[4], pkk[5], pkk[6], pkk[7]);
        }
    }
}

// layer-1 aggregation: LDS node-level counting sort (native int atomics) of
// the bucket segment into colL, then register-accumulating pull (4 threads
// per node, quad shfl reduce -- NO float atomics anywhere), fused epilogue
// h1 = relu(di*acc + b1); pb2 = bf16((h1 @ W2) * di).
__global__ __launch_bounds__(1024) void k_agg1(const int* __restrict__ cnt_b,
                                               const unsigned* __restrict__ packed,
                                               const unsigned short* __restrict__ pb,
                                               const float* __restrict__ dinv,
                                               const float* __restrict__ W2,
                                               const float* __restrict__ b1,
                                               unsigned short* __restrict__ pb2) {
    __shared__ int hist[BKT_NODES];
    __shared__ int beg[BKT_NODES];
    __shared__ int rnk[BKT_NODES];
    __shared__ int wsum[16];
    __shared__ float w2[F_HID * F_HID];
    __shared__ float b1s[F_HID];
    __shared__ int colL[CAP];                       // 40 KiB node-sorted src ids
    __shared__ int tots;
    int b = blockIdx.x, t = threadIdx.x;
    const uint4* pb16 = (const uint4*)pb;
    if (t < BKT_NODES) hist[t] = 0;
    if (t >= 256 && t < 512) w2[t - 256] = W2[t - 256];
    if (t >= 512 && t < 512 + F_HID) b1s[t - 512] = b1[t - 512];
    if (t == 0) tots = min(cnt_b[b], CAP);
    __syncthreads();
    int tot = tots;
    const unsigned* pk = packed + (size_t)b * CAP;
    for (int k = t; k < tot; k += 1024)
        atomicAdd(&hist[pk[k] & 255], 1);           // native ds_add_u32
    __syncthreads();
    int v = (t < BKT_NODES) ? hist[t] : 0;
    int incl = block_incl_scan<16>(v, t, wsum);
    if (t < BKT_NODES) { beg[t] = incl - v; rnk[t] = incl - v; }
    __syncthreads();
    for (int k = t; k < tot; k += 1024) {           // rank-scatter into LDS
        unsigned u = pk[k];
        int r = atomicAdd(&rnk[u & 255], 1);
        colL[r] = (int)(u >> 8);
    }
    __syncthreads();
    int nl = t >> 2, q = t & 3;                     // 4 threads per node
    int node = b * BKT_NODES + nl;
    float f[F_HID];
    if (node < N_NODES && q == 0) {
        unpack16(pb16[node * 2], pb16[node * 2 + 1], f);   // self loop
    } else {
#pragma unroll
        for (int c = 0; c < F_HID; c++) f[c] = 0.0f;
    }
    if (node < N_NODES) {
        int b0 = beg[nl], len = hist[nl];
        for (int i = q; i < len; i += 4) {
            int s = colL[b0 + i];
            uint4 r0 = pb16[s * 2], r1 = pb16[s * 2 + 1];
            float g[F_HID];
            unpack16(r0, r1, g);
#pragma unroll
            for (int c = 0; c < F_HID; c++) f[c] += g[c];
        }
    }
#pragma unroll
    for (int c = 0; c < F_HID; c++) {               // quad reduce (all 4 lanes get sum)
        f[c] += __shfl_xor(f[c], 1, 64);
        f[c] += __shfl_xor(f[c], 2, 64);
    }
    if (node < N_NODES) {
        float di = dinv[node];
        float h[F_HID];
#pragma unroll
        for (int c = 0; c < F_HID; c++)
            h[c] = fmaxf(di * f[c] + b1s[c], 0.0f);
        float m0 = 0.0f, m1 = 0.0f, m2 = 0.0f, m3 = 0.0f;
#pragma unroll
        for (int c = 0; c < F_HID; c++) {           // lane q -> out channels 4q..4q+3
            float4 wv = *(const float4*)&w2[c * F_HID + 4 * q];
            m0 += h[c] * wv.x; m1 += h[c] * wv.y; m2 += h[c] * wv.z; m3 += h[c] * wv.w;
        }
        unsigned p0 = (unsigned)f2bf(m0 * di) | ((unsigned)f2bf(m1 * di) << 16);
        unsigned p1 = (unsigned)f2bf(m2 * di) | ((unsigned)f2bf(m3 * di) << 16);
        *(uint2*)(pb2 + (size_t)node * F_HID + 4 * q) = make_uint2(p0, p1);
    }
}

// layer-2 aggregation + fused mean-pool: same LDS sort + register pull; then
// h2 = relu(di*acc + b2) stored to accT (plain ds_write), and a staggered
// column-scan sums each (local graph, channel); one global atomic per
// (graph,channel) per bucket.
__global__ __launch_bounds__(1024) void k_agg2(const int* __restrict__ cnt_b,
                                               const unsigned* __restrict__ packed,
                                               const unsigned short* __restrict__ pb,
                                               const float* __restrict__ dinv,
                                               const int* __restrict__ batch,
                                               const float* __restrict__ b2,
                                               const float* __restrict__ cnt,
                                               float* __restrict__ out) {
    __shared__ int hist[BKT_NODES];
    __shared__ int beg[BKT_NODES];
    __shared__ int rnk[BKT_NODES];
    __shared__ int wsum[16];
    __shared__ float b2s[F_HID];
    __shared__ float accT[F_HID][BKT_NODES];        // 16 KiB
    __shared__ int bl[BKT_NODES];
    __shared__ int colL[CAP];                       // 40 KiB
    __shared__ int tots;
    int b = blockIdx.x, t = threadIdx.x;
    const uint4* pb16 = (const uint4*)pb;
    if (t < BKT_NODES) {
        hist[t] = 0;
        int nn = b * BKT_NODES + t;
        bl[t] = (nn < N_NODES) ? batch[nn] : -1;
    }
    if (t >= 512 && t < 512 + F_HID) b2s[t - 512] = b2[t - 512];
    if (t == 0) tots = min(cnt_b[b], CAP);
    __syncthreads();
    int tot = tots;
    const unsigned* pk = packed + (size_t)b * CAP;
    for (int k = t; k < tot; k += 1024)
        atomicAdd(&hist[pk[k] & 255], 1);
    __syncthreads();
    int v = (t < BKT_NODES) ? hist[t] : 0;
    int incl = block_incl_scan<16>(v, t, wsum);
    if (t < BKT_NODES) { beg[t] = incl - v; rnk[t] = incl - v; }
    __syncthreads();
    for (int k = t; k < tot; k += 1024) {
        unsigned u = pk[k];
        int r = atomicAdd(&rnk[u & 255], 1);
        colL[r] = (int)(u >> 8);
    }
    __syncthreads();
    int nl = t >> 2, q = t & 3;
    int node = b * BKT_NODES + nl;
    float f[F_HID];
    if (node < N_NODES && q == 0) {
        unpack16(pb16[node * 2], pb16[node * 2 + 1], f);   // self loop
    } else {
#pragma unroll
        for (int c = 0; c < F_HID; c++) f[c] = 0.0f;
    }
    if (node < N_NODES) {
        int b0 = beg[nl], len = hist[nl];
        for (int i = q; i < len; i += 4) {
            int s = colL[b0 + i];
            uint4 r0 = pb16[s * 2], r1 = pb16[s * 2 + 1];
            float g[F_HID];
            unpack16(r0, r1, g);
#pragma unroll
            for (int c = 0; c < F_HID; c++) f[c] += g[c];
        }
    }
#pragma unroll
    for (int c = 0; c < F_HID; c++) {
        f[c] += __shfl_xor(f[c], 1, 64);
        f[c] += __shfl_xor(f[c], 2, 64);
    }
    if (node < N_NODES) {
        float di = dinv[node];
#pragma unroll
        for (int e = 0; e < 4; e++) {               // lane q stores channels 4q..4q+3
            int c = 4 * q + e;
            accT[c][nl] = fmaxf(di * f[c] + b2s[c], 0.0f);
        }
    }
    __syncthreads();
    if (t < 256) {                                  // (local graph l, channel ch)
        int l = t >> 4, ch = t & 15;
        int g = bl[0] + l;
        if (g < N_GRAPHS) {
            float s = 0.0f;
            int m = 0;
            for (int n0 = 0; n0 < 256; n0++) {
                int n = (n0 + ch + 16 * l) & 255;   // bank stagger
                if (bl[n] == g) { s += accT[ch][n]; m++; }
            }
            if (m > 0) atomicAdd(&out[g * F_HID + ch], s / cnt[g]);
        }
    }
}

// ---------------- launcher ----------------

extern "C" void kernel_launch(void* const* d_in, const int* in_sizes, int n_in,
                              void* d_out, int out_size, void* d_ws, size_t ws_size,
                              hipStream_t stream) {
    const float* x     = (const float*)d_in[0];
    const int*   ei    = (const int*)d_in[1];   // [2, N_EDGES]
    const int*   batch = (const int*)d_in[2];
    const float* W1    = (const float*)d_in[3];
    const float* b1    = (const float*)d_in[4];
    const float* W2    = (const float*)d_in[5];
    const float* b2    = (const float*)d_in[6];
    float* out = (float*)d_out;

    int*            H      = (int*)d_ws;                                   // NBLK*HPAD
    int*            cnt_b  = H + (size_t)NBLK * HPAD;                      // 512
    unsigned*       packed = (unsigned*)(cnt_b + 512);                     // NBKT*CAP
    float*          dinv   = (float*)(packed + (size_t)NBKT * CAP);        // N
    unsigned short* pb_a   = (unsigned short*)(dinv + N_NODES);            // N*16 (32B-aligned)
    unsigned short* pb_b   = pb_a + (size_t)N_NODES * F_HID;               // N*16
    float*          cnt    = (float*)(pb_b + (size_t)N_NODES * F_HID);     // 512

    const int* src = ei;
    const int* dst = ei + N_EDGES;

    k_zero<<<(N_GRAPHS * F_HID + 255) / 256, 256, 0, stream>>>(out, cnt);
    k_count<<<NBLK, PBLK, 0, stream>>>(dst, batch, H, cnt);
    k_scan<<<NBKT, 256, 0, stream>>>(H, cnt_b);
    k_scatter<<<NBLK, PBLK, 0, stream>>>(src, dst, H, packed);
    k_deg<<<NBKT, 1024, 0, stream>>>(cnt_b, packed, x, W1, dinv, pb_a);
    k_agg1<<<NBKT, 1024, 0, stream>>>(cnt_b, packed, pb_a, dinv, W2, b1, pb_b);
    k_agg2<<<NBKT, 1024, 0, stream>>>(cnt_b, packed, pb_b, dinv, batch, b2, cnt, out);
}